// Round 5
// baseline (1268.706 us; speedup 1.0000x reference)
//
#include <hip/hip_runtime.h>
#include <hip/hip_bf16.h>
#include <stdint.h>

typedef __bf16 bf16_t;
typedef __bf16 bf16x8 __attribute__((ext_vector_type(8)));
typedef float f32x4 __attribute__((ext_vector_type(4)));

#define D_MODEL 2048
#define SEQ     2048
#define NHEADS  16
#define HDIM    128
#define BATCH   2
#define NTOK    (BATCH * SEQ)                       // 4096
#define NELEM   ((size_t)BATCH * SEQ * D_MODEL)     // 8388608
#define D2      ((size_t)D_MODEL * D_MODEL)         // 4194304

// ---------------------------------------------------------------------------
// fp32 -> bf16 convert pass: x + 6 weights, 8 elems/thread, float4 loads.
// ---------------------------------------------------------------------------
__global__ void __launch_bounds__(256)
cvt7_kernel(const float* __restrict__ x,
            const float* __restrict__ w0, const float* __restrict__ w1,
            const float* __restrict__ w2, const float* __restrict__ w3,
            const float* __restrict__ w4, const float* __restrict__ w5,
            bf16_t* __restrict__ xb, bf16_t* __restrict__ wb) {
  const int y = blockIdx.y;
  const float* srcs[7] = {x, w0, w1, w2, w3, w4, w5};
  const float* src = srcs[y];
  bf16_t* dst = (y == 0) ? xb : wb + (size_t)(y - 1) * D2;
  const size_t n = (y == 0) ? NELEM : D2;
  const size_t base = ((size_t)blockIdx.x * 256 + threadIdx.x) * 8;
  if (base >= n) return;
  f32x4 lo = *(const f32x4*)(src + base);
  f32x4 hi = *(const f32x4*)(src + base + 4);
  union { bf16x8 v; bf16_t h[8]; } u;
#pragma unroll
  for (int j = 0; j < 4; j++) {
    u.h[j]     = (bf16_t)lo[j];
    u.h[j + 4] = (bf16_t)hi[j];
  }
  *(bf16x8*)(dst + base) = u.v;
}

// ---------------------------------------------------------------------------
// async global->LDS 16B helper (global_load_lds_dwordx4).
// ---------------------------------------------------------------------------
__device__ __forceinline__ void async_load16(const void* g, void* l) {
  __builtin_amdgcn_global_load_lds(
      (const __attribute__((address_space(1))) void*)g,
      (__attribute__((address_space(3))) void*)l, 16, 0, 0);
}

// ---------------------------------------------------------------------------
// Legacy 128x128 tile body (m97 structure) — kept for gemm_out (512 wgs of
// 128^2 tile = exactly 2 full occupancy rounds).
// ---------------------------------------------------------------------------
template <int TRANS, typename TC>
__device__ __forceinline__ void gemm_tile_body(const bf16_t* __restrict__ A,
                                               const bf16_t* __restrict__ W,
                                               TC* __restrict__ C) {
  extern __shared__ char smem[];
  bf16_t* As = (bf16_t*)smem;
  bf16_t* Bs = (bf16_t*)smem + 128 * 32;
  const int K = D_MODEL, N = D_MODEL;
  const int tid  = threadIdx.x;
  const int wave = tid >> 6, lane = tid & 63;
  const int quad = lane >> 4, l16 = lane & 15;
  const int tm = blockIdx.x * 128, tn = blockIdx.y * 128;
  const int wm = (wave & 1) * 64, wn = (wave >> 1) * 64;

  f32x4 acc[4][4];
#pragma unroll
  for (int i = 0; i < 4; i++)
#pragma unroll
    for (int j = 0; j < 4; j++) acc[i][j] = (f32x4){0.f, 0.f, 0.f, 0.f};

  const int srow = lane >> 2;
  const int scol = (lane & 3) * 8;

  for (int k0 = 0; k0 < K; k0 += 32) {
    __syncthreads();
#pragma unroll
    for (int i = 0; i < 2; i++) {
      const int rbase = (i * 4 + wave) * 16;
      async_load16(A + (size_t)(tm + rbase + srow) * K + k0 + scol, As + rbase * 32);
      async_load16(W + (size_t)(tn + rbase + srow) * K + k0 + scol, Bs + rbase * 32);
    }
    __syncthreads();

    bf16x8 af[4], bfr[4];
#pragma unroll
    for (int i = 0; i < 4; i++)
      af[i] = *(const bf16x8*)(As + (wm + i * 16 + l16) * 32 + quad * 8);
#pragma unroll
    for (int j = 0; j < 4; j++)
      bfr[j] = *(const bf16x8*)(Bs + (wn + j * 16 + l16) * 32 + quad * 8);
#pragma unroll
    for (int i = 0; i < 4; i++)
#pragma unroll
      for (int j = 0; j < 4; j++)
        acc[i][j] = __builtin_amdgcn_mfma_f32_16x16x32_bf16(af[i], bfr[j], acc[i][j], 0, 0, 0);
  }

#pragma unroll
  for (int i = 0; i < 4; i++) {
    const int r0 = wm + i * 16 + quad * 4;
#pragma unroll
    for (int j = 0; j < 4; j++) {
      const int c = tn + wn + j * 16 + l16;
      if constexpr (TRANS) {
        const int m = tm + r0;
        const int b = m >> 11;
        const int s = m & (SEQ - 1);
        union { bf16_t h[4]; uint2 u2; } p;
#pragma unroll
        for (int r = 0; r < 4; r++) p.h[r] = (bf16_t)acc[i][j][r];
        *(uint2*)((bf16_t*)C + (size_t)(b * D_MODEL + c) * SEQ + s) = p.u2;
      } else {
#pragma unroll
        for (int r = 0; r < 4; r++)
          C[(size_t)(tm + r0 + r) * N + c] = (TC)acc[i][j][r];
      }
    }
  }
}

__global__ void __launch_bounds__(256)
gemm_out_kernel(const bf16_t* __restrict__ A, const bf16_t* __restrict__ W,
                float* __restrict__ C) {
  gemm_tile_body<0, float>(A, W, C);
}

// ---------------------------------------------------------------------------
// 256x256 8-phase GEMM body (m201 template, plain HIP). Unchanged.
// ---------------------------------------------------------------------------
template <int TRANS, typename TC>
__device__ __forceinline__ void gemm256_body(const bf16_t* __restrict__ A,
                                             const bf16_t* __restrict__ W,
                                             TC* __restrict__ C,
                                             const int tm, const int tn) {
  extern __shared__ char smem[];
  constexpr int K = D_MODEL;
  constexpr int NT = K / 64;   // 32 K-tiles
  const int tid = threadIdx.x;
  const int wid = tid >> 6, lane = tid & 63;
  const int quad = lane >> 4, l16 = lane & 15;
  const int wm = wid >> 2, wn = wid & 3;

  const int sr = lane >> 2;
  const int sc = (lane & 3) ^ ((lane >> 4) & 2);
  const int rdoff = (l16 * 64 + quad * 16) ^ ((l16 & 8) << 2);

  f32x4 acc[8][4];
#pragma unroll
  for (int i = 0; i < 8; i++)
#pragma unroll
    for (int j = 0; j < 4; j++) acc[i][j] = (f32x4){0.f, 0.f, 0.f, 0.f};

  bf16x8 af[2][4], bfA[2][2], bfB[2][2];

#define STAGE256(P, rowbase, ldsbase, h, t)                                      \
  {                                                                              \
    const bf16_t* _s = (P) + (size_t)((rowbase) + (h) * 128 + wid * 16 + sr) * K \
                           + ((t) * 64 + sc * 8);                                \
    char* _d = smem + (ldsbase) + (h) * 16384 + wid * 2048;                      \
    async_load16(_s, _d);                                                        \
    async_load16(_s + 32, _d + 1024);                                            \
  }

#define LDA256(c, rh)                                                            \
  _Pragma("unroll") for (int ks = 0; ks < 2; ks++)                               \
  _Pragma("unroll") for (int j = 0; j < 4; j++)                                  \
      af[ks][j] = *(const bf16x8*)(smem + (c) * 65536 +                          \
                  ((wm * 8 + (rh) * 4 + j) * 2 + ks) * 1024 + rdoff);

#define LDB256(c, dst, cf0)                                                      \
  _Pragma("unroll") for (int ks = 0; ks < 2; ks++)                               \
  _Pragma("unroll") for (int j = 0; j < 2; j++)                                  \
      dst[ks][j] = *(const bf16x8*)(smem + (c) * 65536 + 32768 +                 \
                   ((wn * 4 + (cf0) + j) * 2 + ks) * 1024 + rdoff);

#define MFMA16(rh, bfr, cb)                                                      \
  _Pragma("unroll") for (int j = 0; j < 4; j++)                                  \
  _Pragma("unroll") for (int cf = 0; cf < 2; cf++)                               \
  _Pragma("unroll") for (int ks = 0; ks < 2; ks++)                               \
      acc[(rh) * 4 + j][(cb) + cf] = __builtin_amdgcn_mfma_f32_16x16x32_bf16(    \
          af[ks][j], bfr[ks][cf], acc[(rh) * 4 + j][(cb) + cf], 0, 0, 0);

#define BAR256() __builtin_amdgcn_s_barrier()
#define LGKM0()                                                                  \
  { asm volatile("s_waitcnt lgkmcnt(0)" ::: "memory");                           \
    __builtin_amdgcn_sched_barrier(0); }
#define VMW4()                                                                   \
  { asm volatile("s_waitcnt vmcnt(4)" ::: "memory");                             \
    __builtin_amdgcn_sched_barrier(0); }
#define VMW0()                                                                   \
  { asm volatile("s_waitcnt vmcnt(0)" ::: "memory");                             \
    __builtin_amdgcn_sched_barrier(0); }

  STAGE256(A, tm, 0,     0, 0); STAGE256(A, tm, 0,     1, 0);
  STAGE256(W, tn, 32768, 0, 0); STAGE256(W, tn, 32768, 1, 0);
  STAGE256(W, tn, 98304, 0, 1); STAGE256(W, tn, 98304, 1, 1);
  VMW4();
  BAR256();

  for (int it = 0; it < NT / 2; ++it) {
    const int kt = 2 * it;
    const int t2 = (kt + 2 < NT) ? kt + 2 : 0;
    const int t3 = (kt + 3 < NT) ? kt + 3 : 0;

    // P1
    LDA256(0, 0); LDB256(0, bfA, 0);
    STAGE256(A, tm, 65536, 0, kt + 1);
    BAR256(); LGKM0();
    __builtin_amdgcn_s_setprio(1); MFMA16(0, bfA, 0); __builtin_amdgcn_s_setprio(0);
    BAR256();
    // P2
    LDB256(0, bfB, 2);
    STAGE256(A, tm, 65536, 1, kt + 1);
    BAR256(); LGKM0();
    __builtin_amdgcn_s_setprio(1); MFMA16(0, bfB, 2); __builtin_amdgcn_s_setprio(0);
    BAR256();
    // P3
    LDA256(0, 1);
    STAGE256(W, tn, 32768, 0, t2);
    BAR256(); LGKM0();
    __builtin_amdgcn_s_setprio(1); MFMA16(1, bfA, 0); __builtin_amdgcn_s_setprio(0);
    BAR256();
    // P4
    STAGE256(W, tn, 32768, 1, t2);
    BAR256();
    __builtin_amdgcn_s_setprio(1); MFMA16(1, bfB, 2); __builtin_amdgcn_s_setprio(0);
    VMW4();
    BAR256();
    // P5
    LDA256(1, 0); LDB256(1, bfA, 0);
    STAGE256(A, tm, 0, 0, t2);
    BAR256(); LGKM0();
    __builtin_amdgcn_s_setprio(1); MFMA16(0, bfA, 0); __builtin_amdgcn_s_setprio(0);
    BAR256();
    // P6
    LDB256(1, bfB, 2);
    STAGE256(A, tm, 0, 1, t2);
    BAR256(); LGKM0();
    __builtin_amdgcn_s_setprio(1); MFMA16(0, bfB, 2); __builtin_amdgcn_s_setprio(0);
    BAR256();
    // P7
    LDA256(1, 1);
    STAGE256(W, tn, 98304, 0, t3);
    BAR256(); LGKM0();
    __builtin_amdgcn_s_setprio(1); MFMA16(1, bfA, 0); __builtin_amdgcn_s_setprio(0);
    BAR256();
    // P8
    STAGE256(W, tn, 98304, 1, t3);
    BAR256();
    __builtin_amdgcn_s_setprio(1); MFMA16(1, bfB, 2); __builtin_amdgcn_s_setprio(0);
    VMW4();
    BAR256();
  }
  VMW0();

#pragma unroll
  for (int rf = 0; rf < 8; rf++) {
    const int r0 = wm * 128 + rf * 16 + quad * 4;
#pragma unroll
    for (int cf = 0; cf < 4; cf++) {
      const int c = tn + wn * 64 + cf * 16 + l16;
      if constexpr (TRANS) {
        const int m = tm + r0;
        const int b = m >> 11;
        const int s = m & (SEQ - 1);
        union { bf16_t h[4]; uint2 u2; } p;
#pragma unroll
        for (int r = 0; r < 4; r++) p.h[r] = (bf16_t)acc[rf][cf][r];
        *(uint2*)((bf16_t*)C + (size_t)(b * D_MODEL + c) * SEQ + s) = p.u2;
      } else {
#pragma unroll
        for (int r = 0; r < 4; r++)
          C[(size_t)(tm + r0 + r) * D_MODEL + c] = (TC)acc[rf][cf][r];
      }
    }
  }
#undef STAGE256
#undef LDA256
#undef LDB256
#undef MFMA16
#undef BAR256
#undef LGKM0
#undef VMW4
#undef VMW0
}

__global__ void __launch_bounds__(512, 2)
proj5_kernel(const bf16_t* __restrict__ xb, const bf16_t* __restrict__ wb,
             bf16_t* __restrict__ q1, bf16_t* __restrict__ k1,
             bf16_t* __restrict__ q2, bf16_t* __restrict__ k2,
             bf16_t* __restrict__ vt) {
  const int g = blockIdx.y;
  const int orig = blockIdx.x;
  const int wg = (orig & 7) * 16 + (orig >> 3);
  const int tm = (wg & 15) * 256;
  const int tn = (wg >> 4) * 256;
  const bf16_t* w = wb + (size_t)g * D2;
  if (g == 4) {
    gemm256_body<1, bf16_t>(xb, w, vt, tm, tn);
  } else {
    bf16_t* o = (g == 0) ? q1 : (g == 1) ? k1 : (g == 2) ? q2 : k2;
    gemm256_body<0, bf16_t>(xb, w, o, tm, tn);
  }
}

// ---------------------------------------------------------------------------
// Differential flash attention, v8: v7 + T14 async-STAGE split.
//  v7 post-mortem: v4 (2x LDS reads) == v7 in time -> LDS reads were never
//  the limiter; the serial staging (syncthreads; global_load_lds; syncthreads
//  with vmcnt(0) drain) costs ~full load latency per K-tile (~40% of time).
//  v8: reg-staging. Top of tile t: issue 12 global_load_dwordx4 for tile t+1
//  into regs (sched_barrier(0) pins the issue point); compute tile t; after
//  the read-done barrier, ds_write_b128 the regs (vmcnt ~drained by then);
//  barrier; next tile. Global latency hides under ~600cy of MFMA+exp2.
//  Same 2 barriers/tile, LDS 48KB (3 blocks/CU), +48 VGPR in-flight tile
//  (~150 total, under the 168 cap of (256,3)).
// ---------------------------------------------------------------------------
__global__ void __launch_bounds__(256, 3)
diff_attn_kernel(const bf16_t* __restrict__ q1g, const bf16_t* __restrict__ k1g,
                 const bf16_t* __restrict__ q2g, const bf16_t* __restrict__ k2g,
                 const bf16_t* __restrict__ vtg, const float* __restrict__ lamg,
                 bf16_t* __restrict__ outg) {
  const int blk = blockIdx.x;            // 1024 blocks
  const int xcd = blk & 7;
  const int idx = blk >> 3;
  const int bh  = xcd * 4 + (idx >> 5);
  const int qt  = idx & 31;              // 32 q-tiles of 64
  const int b = bh >> 4, h = bh & 15;
  const int tid = threadIdx.x, wave = tid >> 6, lane = tid & 63;
  const int quad = lane >> 4, l16 = lane & 15;
  const int stream = wave >> 1;          // 0: (q1,k1)   1: (q2,k2)
  const int wq     = wave & 1;           // query half of the 64-row tile
  const int q0 = qt * 64 + wq * 32;      // this wave's 32 queries

  __shared__ char smem_all[49152];
  bf16_t* K1s = (bf16_t*)smem_all;              // 16 KB, kappa, XOR-swizzled
  bf16_t* K2s = (bf16_t*)(smem_all + 16384);    // 16 KB
  bf16_t* Vs  = (bf16_t*)(smem_all + 32768);    // 16 KB

  const bf16_t* k1p = k1g + (size_t)b * SEQ * D_MODEL + h * HDIM;
  const bf16_t* k2p = k2g + (size_t)b * SEQ * D_MODEL + h * HDIM;
  const bf16_t* vtp = vtg + ((size_t)b * D_MODEL + h * HDIM) * SEQ;
  const bf16_t* qp  = (stream ? q2g : q1g) +
                      ((size_t)b * SEQ + q0) * D_MODEL + h * HDIM;
  const bf16_t* Ksp = stream ? K2s : K1s;

  // Q fragments for this wave's stream: set a = q0..q0+15, set b = +16..31.
  bf16x8 aqa[4], aqb[4];
#pragma unroll
  for (int c = 0; c < 4; c++) {
    aqa[c] = *(const bf16x8*)(qp + (size_t)l16 * D_MODEL + c * 32 + quad * 8);
    aqb[c] = *(const bf16x8*)(qp + (size_t)(16 + l16) * D_MODEL + c * 32 + quad * 8);
  }

  f32x4 Oa[8], Ob[8];
#pragma unroll
  for (int n = 0; n < 8; n++) {
    Oa[n] = (f32x4){0.f, 0.f, 0.f, 0.f};
    Ob[n] = (f32x4){0.f, 0.f, 0.f, 0.f};
  }
  float la = 0.f, lb = 0.f;

  const float c2 = 0.0883883476483184f * 1.4426950408889634f;  // log2(e)/sqrt(128)

  // ---- per-lane staging geometry (kappa perm + XOR swizzle, as v4-v7) ----
  const int k_r  = lane >> 4;
  const int k_p  = lane & 15;
  const int v_r  = lane >> 3;
  const int v_p  = lane & 7;

  size_t koffs[4], voffs[4];
  int kdst[4], vdst[4];
#pragma unroll
  for (int i = 0; i < 4; i++) {
    const int krb = wave * 16 + i * 4;
    const int kr  = krb + k_r;
    const int kkey = (((kr >> 2) & 3) << 3) | (((kr >> 4) & 1) << 2) |
                     (kr & 3) | (kr & 32);
    const int kg = k_p ^ (kr & 7);
    koffs[i] = (size_t)kkey * D_MODEL + kg * 8;
    kdst[i]  = krb * 128 + lane * 8;
    const int vrb = wave * 32 + i * 8;
    const int vr  = vrb + v_r;
    const int vg  = v_p ^ (vr & 7);
    voffs[i] = (size_t)vr * SEQ + vg * 8;
    vdst[i]  = vrb * 64 + lane * 8;
  }

  uint4 rk1[4], rk2[4], rv[4];

#define LOADT(KT)                                                                \
  {                                                                              \
    const bf16_t* _k1 = k1p + (size_t)(KT) * D_MODEL;                            \
    const bf16_t* _k2 = k2p + (size_t)(KT) * D_MODEL;                            \
    const bf16_t* _vt = vtp + (KT);                                              \
    _Pragma("unroll") for (int i = 0; i < 4; i++) {                              \
      rk1[i] = *(const uint4*)(_k1 + koffs[i]);                                  \
      rk2[i] = *(const uint4*)(_k2 + koffs[i]);                                  \
      rv[i]  = *(const uint4*)(_vt + voffs[i]);                                  \
    }                                                                            \
    __builtin_amdgcn_sched_barrier(0);                                           \
  }

#define STORET()                                                                 \
  {                                                                              \
    _Pragma("unroll") for (int i = 0; i < 4; i++) {                              \
      *(uint4*)(K1s + kdst[i]) = rk1[i];                                         \
      *(uint4*)(K2s + kdst[i]) = rk2[i];                                         \
      *(uint4*)(Vs  + vdst[i]) = rv[i];                                          \
    }                                                                            \
  }

  // ---- prologue: stage tile 0 ----
  LOADT(0);
  STORET();
  __syncthreads();

  for (int kt = 0; kt < SEQ; kt += 64) {
    const int nxt = kt + 64;
    if (nxt < SEQ) LOADT(nxt);   // in flight during this tile's compute

    const int xsw = l16 & 7;

    // ---- S^T: all 4 subtiles live, c-outer -> 8 indep MFMA chains ----
    f32x4 sa[4], sb[4];
#pragma unroll
    for (int s = 0; s < 4; s++) {
      sa[s] = (f32x4){0.f, 0.f, 0.f, 0.f};
      sb[s] = (f32x4){0.f, 0.f, 0.f, 0.f};
    }
#pragma unroll
    for (int c = 0; c < 4; c++) {
      const int pos = ((c * 4 + quad) ^ xsw) * 8;
#pragma unroll
      for (int s = 0; s < 4; s++) {
        bf16x8 f = *(const bf16x8*)(Ksp + (s * 16 + l16) * 128 + pos);
        sa[s] = __builtin_amdgcn_mfma_f32_16x16x32_bf16(f, aqa[c], sa[s], 0, 0, 0);
        sb[s] = __builtin_amdgcn_mfma_f32_16x16x32_bf16(f, aqb[c], sb[s], 0, 0, 0);
      }
    }

    // ---- softmax pack, both halves (releases sa/sb before PV) ----
    union { bf16x8 v; bf16_t h[8]; } pa[2], pb[2];
#pragma unroll
    for (int s = 0; s < 4; s++) {
#pragma unroll
      for (int r = 0; r < 4; r++) {
        const float ea = __builtin_amdgcn_exp2f(sa[s][r] * c2);
        const float eb = __builtin_amdgcn_exp2f(sb[s][r] * c2);
        pa[s >> 1].h[(s & 1) * 4 + r] = (bf16_t)ea; la += ea;
        pb[s >> 1].h[(s & 1) * 4 + r] = (bf16_t)eb; lb += eb;
      }
    }

    // ---- PV: one V-frag read feeds 2 MFMAs; 16 indep chains ----
#pragma unroll
    for (int half = 0; half < 2; half++) {
      const int vpos = ((half * 4 + quad) ^ xsw) * 8;
#pragma unroll
      for (int n = 0; n < 8; n++) {
        bf16x8 vf = *(const bf16x8*)(Vs + (n * 16 + l16) * 64 + vpos);
        Oa[n] = __builtin_amdgcn_mfma_f32_16x16x32_bf16(pa[half].v, vf, Oa[n], 0, 0, 0);
        Ob[n] = __builtin_amdgcn_mfma_f32_16x16x32_bf16(pb[half].v, vf, Ob[n], 0, 0, 0);
      }
    }

    __syncthreads();             // all waves done reading this tile's LDS
    if (nxt < SEQ) {
      STORET();                  // vmcnt auto-wait (loads ~600cy old)
      __syncthreads();           // writes visible before next compute
    }
  }
#undef LOADT
#undef STORET

  // ---- denominators (per set, within wave) ----
  la += __shfl_xor(la, 16); la += __shfl_xor(la, 32);
  lb += __shfl_xor(lb, 16); lb += __shfl_xor(lb, 32);

  // ---- cross-stream combine through LDS (reuse retired K buffers) ----
  __syncthreads();                       // all K/V reads done
  float* xfer = (float*)smem_all;        // 64 rows x 128 f32 = 32 KB

  if (stream == 1) {
    const float lam = lamg[h];
    const float ia = lam / la, ib = lam / lb;
    float iao[4], ibo[4];
#pragma unroll
    for (int r = 0; r < 4; r++) {
      iao[r] = __shfl(ia, quad * 4 + r, 16);
      ibo[r] = __shfl(ib, quad * 4 + r, 16);
    }
#pragma unroll
    for (int r = 0; r < 4; r++)
#pragma unroll
      for (int n = 0; n < 8; n++) {
        xfer[(wq * 32 + quad * 4 + r) * 128 + n * 16 + l16] = Oa[n][r] * iao[r];
        xfer[(wq * 32 + 16 + quad * 4 + r) * 128 + n * 16 + l16] = Ob[n][r] * ibo[r];
      }
  }
  __syncthreads();
  if (stream == 0) {
    const float ia = 1.f / la, ib = 1.f / lb;
    float iao[4], ibo[4];
#pragma unroll
    for (int r = 0; r < 4; r++) {
      iao[r] = __shfl(ia, quad * 4 + r, 16);
      ibo[r] = __shfl(ib, quad * 4 + r, 16);
    }
    bf16_t* op = outg + ((size_t)b * SEQ + q0) * D_MODEL + h * HDIM;
#pragma unroll
    for (int r = 0; r < 4; r++)
#pragma unroll
      for (int n = 0; n < 8; n++) {
        const float va = Oa[n][r] * iao[r] -
                         xfer[(wq * 32 + quad * 4 + r) * 128 + n * 16 + l16];
        const float vb = Ob[n][r] * ibo[r] -
                         xfer[(wq * 32 + 16 + quad * 4 + r) * 128 + n * 16 + l16];
        op[(size_t)(quad * 4 + r) * D_MODEL + n * 16 + l16] = (bf16_t)va;
        op[(size_t)(16 + quad * 4 + r) * D_MODEL + n * 16 + l16] = (bf16_t)vb;
      }
  }
}

// ---------------------------------------------------------------------------
extern "C" void kernel_launch(void* const* d_in, const int* in_sizes, int n_in,
                              void* d_out, int out_size, void* d_ws, size_t ws_size,
                              hipStream_t stream) {
  const float* x   = (const float*)d_in[0];
  const float* wq1 = (const float*)d_in[1];
  const float* wk1 = (const float*)d_in[2];
  const float* wq2 = (const float*)d_in[3];
  const float* wk2 = (const float*)d_in[4];
  const float* wv  = (const float*)d_in[5];
  const float* wo  = (const float*)d_in[6];
  const float* lam = (const float*)d_in[7];

  bf16_t* ws = (bf16_t*)d_ws;
  bf16_t* q1 = ws + 0 * NELEM;
  bf16_t* k1 = ws + 1 * NELEM;
  bf16_t* q2 = ws + 2 * NELEM;
  bf16_t* k2 = ws + 3 * NELEM;
  bf16_t* vt = ws + 4 * NELEM;   // [B, D, S] channel-major (V transposed)
  bf16_t* xb = ws + 5 * NELEM;   // bf16 copy of x; later reused as `ao`
  bf16_t* ao = xb;               // alias: xb dead once proj5 completes
  bf16_t* wb = ws + 6 * NELEM;   // 6 bf16 weights [wq1,wk1,wq2,wk2,wv,wo]

  // one-time: allow 128 KiB dynamic LDS for the 8-phase GEMM
  static bool attr_set = false;
  if (!attr_set) {
    (void)hipFuncSetAttribute(reinterpret_cast<const void*>(proj5_kernel),
                              hipFuncAttributeMaxDynamicSharedMemorySize, 131072);
    attr_set = true;
  }

  cvt7_kernel<<<dim3(4096, 7), dim3(256), 0, stream>>>(
      x, wq1, wk1, wq2, wk2, wv, wo, xb, wb);
  proj5_kernel<<<dim3(128, 5), dim3(512), 131072, stream>>>(
      xb, wb, q1, k1, q2, k2, vt);
  diff_attn_kernel<<<dim3(BATCH * NHEADS * (SEQ / 64)), dim3(256), 0, stream>>>(
      q1, k1, q2, k2, vt, lam, ao);
  gemm_out_kernel<<<dim3(NTOK / 128, D_MODEL / 128), dim3(256), 16384, stream>>>(
      ao, wb + 5 * D2, (float*)d_out);
}

// Round 6
// 893.515 us; speedup vs baseline: 1.4199x; 1.4199x over previous
//
#include <hip/hip_runtime.h>
#include <hip/hip_bf16.h>
#include <stdint.h>

typedef __bf16 bf16_t;
typedef __bf16 bf16x8 __attribute__((ext_vector_type(8)));
typedef float f32x4 __attribute__((ext_vector_type(4)));

#define D_MODEL 2048
#define SEQ     2048
#define NHEADS  16
#define HDIM    128
#define BATCH   2
#define NTOK    (BATCH * SEQ)                       // 4096
#define NELEM   ((size_t)BATCH * SEQ * D_MODEL)     // 8388608
#define D2      ((size_t)D_MODEL * D_MODEL)         // 4194304

// ---------------------------------------------------------------------------
// fp32 -> bf16 convert pass: x + 6 weights, 8 elems/thread, float4 loads.
// ---------------------------------------------------------------------------
__global__ void __launch_bounds__(256)
cvt7_kernel(const float* __restrict__ x,
            const float* __restrict__ w0, const float* __restrict__ w1,
            const float* __restrict__ w2, const float* __restrict__ w3,
            const float* __restrict__ w4, const float* __restrict__ w5,
            bf16_t* __restrict__ xb, bf16_t* __restrict__ wb) {
  const int y = blockIdx.y;
  const float* srcs[7] = {x, w0, w1, w2, w3, w4, w5};
  const float* src = srcs[y];
  bf16_t* dst = (y == 0) ? xb : wb + (size_t)(y - 1) * D2;
  const size_t n = (y == 0) ? NELEM : D2;
  const size_t base = ((size_t)blockIdx.x * 256 + threadIdx.x) * 8;
  if (base >= n) return;
  f32x4 lo = *(const f32x4*)(src + base);
  f32x4 hi = *(const f32x4*)(src + base + 4);
  union { bf16x8 v; bf16_t h[8]; } u;
#pragma unroll
  for (int j = 0; j < 4; j++) {
    u.h[j]     = (bf16_t)lo[j];
    u.h[j + 4] = (bf16_t)hi[j];
  }
  *(bf16x8*)(dst + base) = u.v;
}

// ---------------------------------------------------------------------------
// async global->LDS 16B helper (global_load_lds_dwordx4).
// ---------------------------------------------------------------------------
__device__ __forceinline__ void async_load16(const void* g, void* l) {
  __builtin_amdgcn_global_load_lds(
      (const __attribute__((address_space(1))) void*)g,
      (__attribute__((address_space(3))) void*)l, 16, 0, 0);
}

// ---------------------------------------------------------------------------
// Legacy 128x128 tile body (m97 structure) — kept for gemm_out (512 wgs of
// 128^2 tile = exactly 2 full occupancy rounds).
// ---------------------------------------------------------------------------
template <int TRANS, typename TC>
__device__ __forceinline__ void gemm_tile_body(const bf16_t* __restrict__ A,
                                               const bf16_t* __restrict__ W,
                                               TC* __restrict__ C) {
  extern __shared__ char smem[];
  bf16_t* As = (bf16_t*)smem;
  bf16_t* Bs = (bf16_t*)smem + 128 * 32;
  const int K = D_MODEL, N = D_MODEL;
  const int tid  = threadIdx.x;
  const int wave = tid >> 6, lane = tid & 63;
  const int quad = lane >> 4, l16 = lane & 15;
  const int tm = blockIdx.x * 128, tn = blockIdx.y * 128;
  const int wm = (wave & 1) * 64, wn = (wave >> 1) * 64;

  f32x4 acc[4][4];
#pragma unroll
  for (int i = 0; i < 4; i++)
#pragma unroll
    for (int j = 0; j < 4; j++) acc[i][j] = (f32x4){0.f, 0.f, 0.f, 0.f};

  const int srow = lane >> 2;
  const int scol = (lane & 3) * 8;

  for (int k0 = 0; k0 < K; k0 += 32) {
    __syncthreads();
#pragma unroll
    for (int i = 0; i < 2; i++) {
      const int rbase = (i * 4 + wave) * 16;
      async_load16(A + (size_t)(tm + rbase + srow) * K + k0 + scol, As + rbase * 32);
      async_load16(W + (size_t)(tn + rbase + srow) * K + k0 + scol, Bs + rbase * 32);
    }
    __syncthreads();

    bf16x8 af[4], bfr[4];
#pragma unroll
    for (int i = 0; i < 4; i++)
      af[i] = *(const bf16x8*)(As + (wm + i * 16 + l16) * 32 + quad * 8);
#pragma unroll
    for (int j = 0; j < 4; j++)
      bfr[j] = *(const bf16x8*)(Bs + (wn + j * 16 + l16) * 32 + quad * 8);
#pragma unroll
    for (int i = 0; i < 4; i++)
#pragma unroll
      for (int j = 0; j < 4; j++)
        acc[i][j] = __builtin_amdgcn_mfma_f32_16x16x32_bf16(af[i], bfr[j], acc[i][j], 0, 0, 0);
  }

#pragma unroll
  for (int i = 0; i < 4; i++) {
    const int r0 = wm + i * 16 + quad * 4;
#pragma unroll
    for (int j = 0; j < 4; j++) {
      const int c = tn + wn + j * 16 + l16;
      if constexpr (TRANS) {
        const int m = tm + r0;
        const int b = m >> 11;
        const int s = m & (SEQ - 1);
        union { bf16_t h[4]; uint2 u2; } p;
#pragma unroll
        for (int r = 0; r < 4; r++) p.h[r] = (bf16_t)acc[i][j][r];
        *(uint2*)((bf16_t*)C + (size_t)(b * D_MODEL + c) * SEQ + s) = p.u2;
      } else {
#pragma unroll
        for (int r = 0; r < 4; r++)
          C[(size_t)(tm + r0 + r) * N + c] = (TC)acc[i][j][r];
      }
    }
  }
}

__global__ void __launch_bounds__(256)
gemm_out_kernel(const bf16_t* __restrict__ A, const bf16_t* __restrict__ W,
                float* __restrict__ C) {
  gemm_tile_body<0, float>(A, W, C);
}

// ---------------------------------------------------------------------------
// 256x256 8-phase GEMM body (m201 template, plain HIP). Unchanged.
// ---------------------------------------------------------------------------
template <int TRANS, typename TC>
__device__ __forceinline__ void gemm256_body(const bf16_t* __restrict__ A,
                                             const bf16_t* __restrict__ W,
                                             TC* __restrict__ C,
                                             const int tm, const int tn) {
  extern __shared__ char smem[];
  constexpr int K = D_MODEL;
  constexpr int NT = K / 64;   // 32 K-tiles
  const int tid = threadIdx.x;
  const int wid = tid >> 6, lane = tid & 63;
  const int quad = lane >> 4, l16 = lane & 15;
  const int wm = wid >> 2, wn = wid & 3;

  const int sr = lane >> 2;
  const int sc = (lane & 3) ^ ((lane >> 4) & 2);
  const int rdoff = (l16 * 64 + quad * 16) ^ ((l16 & 8) << 2);

  f32x4 acc[8][4];
#pragma unroll
  for (int i = 0; i < 8; i++)
#pragma unroll
    for (int j = 0; j < 4; j++) acc[i][j] = (f32x4){0.f, 0.f, 0.f, 0.f};

  bf16x8 af[2][4], bfA[2][2], bfB[2][2];

#define STAGE256(P, rowbase, ldsbase, h, t)                                      \
  {                                                                              \
    const bf16_t* _s = (P) + (size_t)((rowbase) + (h) * 128 + wid * 16 + sr) * K \
                           + ((t) * 64 + sc * 8);                                \
    char* _d = smem + (ldsbase) + (h) * 16384 + wid * 2048;                      \
    async_load16(_s, _d);                                                        \
    async_load16(_s + 32, _d + 1024);                                            \
  }

#define LDA256(c, rh)                                                            \
  _Pragma("unroll") for (int ks = 0; ks < 2; ks++)                               \
  _Pragma("unroll") for (int j = 0; j < 4; j++)                                  \
      af[ks][j] = *(const bf16x8*)(smem + (c) * 65536 +                          \
                  ((wm * 8 + (rh) * 4 + j) * 2 + ks) * 1024 + rdoff);

#define LDB256(c, dst, cf0)                                                      \
  _Pragma("unroll") for (int ks = 0; ks < 2; ks++)                               \
  _Pragma("unroll") for (int j = 0; j < 2; j++)                                  \
      dst[ks][j] = *(const bf16x8*)(smem + (c) * 65536 + 32768 +                 \
                   ((wn * 4 + (cf0) + j) * 2 + ks) * 1024 + rdoff);

#define MFMA16(rh, bfr, cb)                                                      \
  _Pragma("unroll") for (int j = 0; j < 4; j++)                                  \
  _Pragma("unroll") for (int cf = 0; cf < 2; cf++)                               \
  _Pragma("unroll") for (int ks = 0; ks < 2; ks++)                               \
      acc[(rh) * 4 + j][(cb) + cf] = __builtin_amdgcn_mfma_f32_16x16x32_bf16(    \
          af[ks][j], bfr[ks][cf], acc[(rh) * 4 + j][(cb) + cf], 0, 0, 0);

#define BAR256() __builtin_amdgcn_s_barrier()
#define LGKM0()                                                                  \
  { asm volatile("s_waitcnt lgkmcnt(0)" ::: "memory");                           \
    __builtin_amdgcn_sched_barrier(0); }
#define VMW4()                                                                   \
  { asm volatile("s_waitcnt vmcnt(4)" ::: "memory");                             \
    __builtin_amdgcn_sched_barrier(0); }
#define VMW0()                                                                   \
  { asm volatile("s_waitcnt vmcnt(0)" ::: "memory");                             \
    __builtin_amdgcn_sched_barrier(0); }

  STAGE256(A, tm, 0,     0, 0); STAGE256(A, tm, 0,     1, 0);
  STAGE256(W, tn, 32768, 0, 0); STAGE256(W, tn, 32768, 1, 0);
  STAGE256(W, tn, 98304, 0, 1); STAGE256(W, tn, 98304, 1, 1);
  VMW4();
  BAR256();

  for (int it = 0; it < NT / 2; ++it) {
    const int kt = 2 * it;
    const int t2 = (kt + 2 < NT) ? kt + 2 : 0;
    const int t3 = (kt + 3 < NT) ? kt + 3 : 0;

    // P1
    LDA256(0, 0); LDB256(0, bfA, 0);
    STAGE256(A, tm, 65536, 0, kt + 1);
    BAR256(); LGKM0();
    __builtin_amdgcn_s_setprio(1); MFMA16(0, bfA, 0); __builtin_amdgcn_s_setprio(0);
    BAR256();
    // P2
    LDB256(0, bfB, 2);
    STAGE256(A, tm, 65536, 1, kt + 1);
    BAR256(); LGKM0();
    __builtin_amdgcn_s_setprio(1); MFMA16(0, bfB, 2); __builtin_amdgcn_s_setprio(0);
    BAR256();
    // P3
    LDA256(0, 1);
    STAGE256(W, tn, 32768, 0, t2);
    BAR256(); LGKM0();
    __builtin_amdgcn_s_setprio(1); MFMA16(1, bfA, 0); __builtin_amdgcn_s_setprio(0);
    BAR256();
    // P4
    STAGE256(W, tn, 32768, 1, t2);
    BAR256();
    __builtin_amdgcn_s_setprio(1); MFMA16(1, bfB, 2); __builtin_amdgcn_s_setprio(0);
    VMW4();
    BAR256();
    // P5
    LDA256(1, 0); LDB256(1, bfA, 0);
    STAGE256(A, tm, 0, 0, t2);
    BAR256(); LGKM0();
    __builtin_amdgcn_s_setprio(1); MFMA16(0, bfA, 0); __builtin_amdgcn_s_setprio(0);
    BAR256();
    // P6
    LDB256(1, bfB, 2);
    STAGE256(A, tm, 0, 1, t2);
    BAR256(); LGKM0();
    __builtin_amdgcn_s_setprio(1); MFMA16(0, bfB, 2); __builtin_amdgcn_s_setprio(0);
    BAR256();
    // P7
    LDA256(1, 1);
    STAGE256(W, tn, 98304, 0, t3);
    BAR256(); LGKM0();
    __builtin_amdgcn_s_setprio(1); MFMA16(1, bfA, 0); __builtin_amdgcn_s_setprio(0);
    BAR256();
    // P8
    STAGE256(W, tn, 98304, 1, t3);
    BAR256();
    __builtin_amdgcn_s_setprio(1); MFMA16(1, bfB, 2); __builtin_amdgcn_s_setprio(0);
    VMW4();
    BAR256();
  }
  VMW0();

#pragma unroll
  for (int rf = 0; rf < 8; rf++) {
    const int r0 = wm * 128 + rf * 16 + quad * 4;
#pragma unroll
    for (int cf = 0; cf < 4; cf++) {
      const int c = tn + wn * 64 + cf * 16 + l16;
      if constexpr (TRANS) {
        const int m = tm + r0;
        const int b = m >> 11;
        const int s = m & (SEQ - 1);
        union { bf16_t h[4]; uint2 u2; } p;
#pragma unroll
        for (int r = 0; r < 4; r++) p.h[r] = (bf16_t)acc[rf][cf][r];
        *(uint2*)((bf16_t*)C + (size_t)(b * D_MODEL + c) * SEQ + s) = p.u2;
      } else {
#pragma unroll
        for (int r = 0; r < 4; r++)
          C[(size_t)(tm + r0 + r) * D_MODEL + c] = (TC)acc[rf][cf][r];
      }
    }
  }
#undef STAGE256
#undef LDA256
#undef LDB256
#undef MFMA16
#undef BAR256
#undef LGKM0
#undef VMW4
#undef VMW0
}

__global__ void __launch_bounds__(512, 2)
proj5_kernel(const bf16_t* __restrict__ xb, const bf16_t* __restrict__ wb,
             bf16_t* __restrict__ q1, bf16_t* __restrict__ k1,
             bf16_t* __restrict__ q2, bf16_t* __restrict__ k2,
             bf16_t* __restrict__ vt) {
  const int g = blockIdx.y;
  const int orig = blockIdx.x;
  const int wg = (orig & 7) * 16 + (orig >> 3);
  const int tm = (wg & 15) * 256;
  const int tn = (wg >> 4) * 256;
  const bf16_t* w = wb + (size_t)g * D2;
  if (g == 4) {
    gemm256_body<1, bf16_t>(xb, w, vt, tm, tn);
  } else {
    bf16_t* o = (g == 0) ? q1 : (g == 1) ? k1 : (g == 2) ? q2 : k2;
    gemm256_body<0, bf16_t>(xb, w, o, tm, tn);
  }
}

// ---------------------------------------------------------------------------
// Differential flash attention, v9: v8 (T14 async-STAGE) with the register
//  cap FIXED. v8 post-mortem: __launch_bounds__(256,3) capped unified
//  VGPR+AGPR at ~170; the 48 in-flight staging VGPRs spilled -> 2GB scratch
//  writes/tile. KEY: v7's measured occupancy was already 24.9% = 8 waves/CU
//  (the ",3" hint was never honored — unified reg use ~184 > 128-tier). So
//  (256,2) raises the allocator cap to 256 with ZERO occupancy change.
//  Live set ~230 unified: O 64 + staging 48 + Q 32 + S/P ~40 + addr ~30.
// ---------------------------------------------------------------------------
__global__ void __launch_bounds__(256, 2)
diff_attn_kernel(const bf16_t* __restrict__ q1g, const bf16_t* __restrict__ k1g,
                 const bf16_t* __restrict__ q2g, const bf16_t* __restrict__ k2g,
                 const bf16_t* __restrict__ vtg, const float* __restrict__ lamg,
                 bf16_t* __restrict__ outg) {
  const int blk = blockIdx.x;            // 1024 blocks
  const int xcd = blk & 7;
  const int idx = blk >> 3;
  const int bh  = xcd * 4 + (idx >> 5);
  const int qt  = idx & 31;              // 32 q-tiles of 64
  const int b = bh >> 4, h = bh & 15;
  const int tid = threadIdx.x, wave = tid >> 6, lane = tid & 63;
  const int quad = lane >> 4, l16 = lane & 15;
  const int stream = wave >> 1;          // 0: (q1,k1)   1: (q2,k2)
  const int wq     = wave & 1;           // query half of the 64-row tile
  const int q0 = qt * 64 + wq * 32;      // this wave's 32 queries

  __shared__ char smem_all[49152];
  bf16_t* K1s = (bf16_t*)smem_all;              // 16 KB, kappa, XOR-swizzled
  bf16_t* K2s = (bf16_t*)(smem_all + 16384);    // 16 KB
  bf16_t* Vs  = (bf16_t*)(smem_all + 32768);    // 16 KB

  const bf16_t* k1p = k1g + (size_t)b * SEQ * D_MODEL + h * HDIM;
  const bf16_t* k2p = k2g + (size_t)b * SEQ * D_MODEL + h * HDIM;
  const bf16_t* vtp = vtg + ((size_t)b * D_MODEL + h * HDIM) * SEQ;
  const bf16_t* qp  = (stream ? q2g : q1g) +
                      ((size_t)b * SEQ + q0) * D_MODEL + h * HDIM;
  const bf16_t* Ksp = stream ? K2s : K1s;

  // Q fragments for this wave's stream: set a = q0..q0+15, set b = +16..31.
  bf16x8 aqa[4], aqb[4];
#pragma unroll
  for (int c = 0; c < 4; c++) {
    aqa[c] = *(const bf16x8*)(qp + (size_t)l16 * D_MODEL + c * 32 + quad * 8);
    aqb[c] = *(const bf16x8*)(qp + (size_t)(16 + l16) * D_MODEL + c * 32 + quad * 8);
  }

  f32x4 Oa[8], Ob[8];
#pragma unroll
  for (int n = 0; n < 8; n++) {
    Oa[n] = (f32x4){0.f, 0.f, 0.f, 0.f};
    Ob[n] = (f32x4){0.f, 0.f, 0.f, 0.f};
  }
  float la = 0.f, lb = 0.f;

  const float c2 = 0.0883883476483184f * 1.4426950408889634f;  // log2(e)/sqrt(128)

  // ---- per-lane staging geometry (kappa perm + XOR swizzle, as v4-v7) ----
  const int k_r  = lane >> 4;
  const int k_p  = lane & 15;
  const int v_r  = lane >> 3;
  const int v_p  = lane & 7;

  size_t koffs[4], voffs[4];
  int kdst[4], vdst[4];
#pragma unroll
  for (int i = 0; i < 4; i++) {
    const int krb = wave * 16 + i * 4;
    const int kr  = krb + k_r;
    const int kkey = (((kr >> 2) & 3) << 3) | (((kr >> 4) & 1) << 2) |
                     (kr & 3) | (kr & 32);
    const int kg = k_p ^ (kr & 7);
    koffs[i] = (size_t)kkey * D_MODEL + kg * 8;
    kdst[i]  = krb * 128 + lane * 8;
    const int vrb = wave * 32 + i * 8;
    const int vr  = vrb + v_r;
    const int vg  = v_p ^ (vr & 7);
    voffs[i] = (size_t)vr * SEQ + vg * 8;
    vdst[i]  = vrb * 64 + lane * 8;
  }

  uint4 rk1[4], rk2[4], rv[4];

#define LOADT(KT)                                                                \
  {                                                                              \
    const bf16_t* _k1 = k1p + (size_t)(KT) * D_MODEL;                            \
    const bf16_t* _k2 = k2p + (size_t)(KT) * D_MODEL;                            \
    const bf16_t* _vt = vtp + (KT);                                              \
    _Pragma("unroll") for (int i = 0; i < 4; i++) {                              \
      rk1[i] = *(const uint4*)(_k1 + koffs[i]);                                  \
      rk2[i] = *(const uint4*)(_k2 + koffs[i]);                                  \
      rv[i]  = *(const uint4*)(_vt + voffs[i]);                                  \
    }                                                                            \
    __builtin_amdgcn_sched_barrier(0);                                           \
  }

#define STORET()                                                                 \
  {                                                                              \
    _Pragma("unroll") for (int i = 0; i < 4; i++) {                              \
      *(uint4*)(K1s + kdst[i]) = rk1[i];                                         \
      *(uint4*)(K2s + kdst[i]) = rk2[i];                                         \
      *(uint4*)(Vs  + vdst[i]) = rv[i];                                          \
    }                                                                            \
  }

  // ---- prologue: stage tile 0 ----
  LOADT(0);
  STORET();
  __syncthreads();

  for (int kt = 0; kt < SEQ; kt += 64) {
    const int nxt = kt + 64;
    if (nxt < SEQ) LOADT(nxt);   // in flight during this tile's compute

    const int xsw = l16 & 7;

    // ---- S^T: all 4 subtiles live, c-outer -> 8 indep MFMA chains ----
    f32x4 sa[4], sb[4];
#pragma unroll
    for (int s = 0; s < 4; s++) {
      sa[s] = (f32x4){0.f, 0.f, 0.f, 0.f};
      sb[s] = (f32x4){0.f, 0.f, 0.f, 0.f};
    }
#pragma unroll
    for (int c = 0; c < 4; c++) {
      const int pos = ((c * 4 + quad) ^ xsw) * 8;
#pragma unroll
      for (int s = 0; s < 4; s++) {
        bf16x8 f = *(const bf16x8*)(Ksp + (s * 16 + l16) * 128 + pos);
        sa[s] = __builtin_amdgcn_mfma_f32_16x16x32_bf16(f, aqa[c], sa[s], 0, 0, 0);
        sb[s] = __builtin_amdgcn_mfma_f32_16x16x32_bf16(f, aqb[c], sb[s], 0, 0, 0);
      }
    }

    // ---- softmax pack, both halves (releases sa/sb before PV) ----
    union { bf16x8 v; bf16_t h[8]; } pa[2], pb[2];
#pragma unroll
    for (int s = 0; s < 4; s++) {
#pragma unroll
      for (int r = 0; r < 4; r++) {
        const float ea = __builtin_amdgcn_exp2f(sa[s][r] * c2);
        const float eb = __builtin_amdgcn_exp2f(sb[s][r] * c2);
        pa[s >> 1].h[(s & 1) * 4 + r] = (bf16_t)ea; la += ea;
        pb[s >> 1].h[(s & 1) * 4 + r] = (bf16_t)eb; lb += eb;
      }
    }

    // ---- PV: one V-frag read feeds 2 MFMAs; 16 indep chains ----
#pragma unroll
    for (int half = 0; half < 2; half++) {
      const int vpos = ((half * 4 + quad) ^ xsw) * 8;
#pragma unroll
      for (int n = 0; n < 8; n++) {
        bf16x8 vf = *(const bf16x8*)(Vs + (n * 16 + l16) * 64 + vpos);
        Oa[n] = __builtin_amdgcn_mfma_f32_16x16x32_bf16(pa[half].v, vf, Oa[n], 0, 0, 0);
        Ob[n] = __builtin_amdgcn_mfma_f32_16x16x32_bf16(pb[half].v, vf, Ob[n], 0, 0, 0);
      }
    }

    __syncthreads();             // all waves done reading this tile's LDS
    if (nxt < SEQ) {
      STORET();                  // vmcnt auto-wait (loads ~600cy old)
      __syncthreads();           // writes visible before next compute
    }
  }
#undef LOADT
#undef STORET

  // ---- denominators (per set, within wave) ----
  la += __shfl_xor(la, 16); la += __shfl_xor(la, 32);
  lb += __shfl_xor(lb, 16); lb += __shfl_xor(lb, 32);

  // ---- cross-stream combine through LDS (reuse retired K buffers) ----
  __syncthreads();                       // all K/V reads done
  float* xfer = (float*)smem_all;        // 64 rows x 128 f32 = 32 KB

  if (stream == 1) {
    const float lam = lamg[h];
    const float ia = lam / la, ib = lam / lb;
    float iao[4], ibo[4];
#pragma unroll
    for (int r = 0; r < 4; r++) {
      iao[r] = __shfl(ia, quad * 4 + r, 16);
      ibo[r] = __shfl(ib, quad * 4 + r, 16);
    }
#pragma unroll
    for (int r = 0; r < 4; r++)
#pragma unroll
      for (int n = 0; n < 8; n++) {
        xfer[(wq * 32 + quad * 4 + r) * 128 + n * 16 + l16] = Oa[n][r] * iao[r];
        xfer[(wq * 32 + 16 + quad * 4 + r) * 128 + n * 16 + l16] = Ob[n][r] * ibo[r];
      }
  }
  __syncthreads();
  if (stream == 0) {
    const float ia = 1.f / la, ib = 1.f / lb;
    float iao[4], ibo[4];
#pragma unroll
    for (int r = 0; r < 4; r++) {
      iao[r] = __shfl(ia, quad * 4 + r, 16);
      ibo[r] = __shfl(ib, quad * 4 + r, 16);
    }
    bf16_t* op = outg + ((size_t)b * SEQ + q0) * D_MODEL + h * HDIM;
#pragma unroll
    for (int r = 0; r < 4; r++)
#pragma unroll
      for (int n = 0; n < 8; n++) {
        const float va = Oa[n][r] * iao[r] -
                         xfer[(wq * 32 + quad * 4 + r) * 128 + n * 16 + l16];
        const float vb = Ob[n][r] * ibo[r] -
                         xfer[(wq * 32 + 16 + quad * 4 + r) * 128 + n * 16 + l16];
        op[(size_t)(quad * 4 + r) * D_MODEL + n * 16 + l16] = (bf16_t)va;
        op[(size_t)(16 + quad * 4 + r) * D_MODEL + n * 16 + l16] = (bf16_t)vb;
      }
  }
}

// ---------------------------------------------------------------------------
extern "C" void kernel_launch(void* const* d_in, const int* in_sizes, int n_in,
                              void* d_out, int out_size, void* d_ws, size_t ws_size,
                              hipStream_t stream) {
  const float* x   = (const float*)d_in[0];
  const float* wq1 = (const float*)d_in[1];
  const float* wk1 = (const float*)d_in[2];
  const float* wq2 = (const float*)d_in[3];
  const float* wk2 = (const float*)d_in[4];
  const float* wv  = (const float*)d_in[5];
  const float* wo  = (const float*)d_in[6];
  const float* lam = (const float*)d_in[7];

  bf16_t* ws = (bf16_t*)d_ws;
  bf16_t* q1 = ws + 0 * NELEM;
  bf16_t* k1 = ws + 1 * NELEM;
  bf16_t* q2 = ws + 2 * NELEM;
  bf16_t* k2 = ws + 3 * NELEM;
  bf16_t* vt = ws + 4 * NELEM;   // [B, D, S] channel-major (V transposed)
  bf16_t* xb = ws + 5 * NELEM;   // bf16 copy of x; later reused as `ao`
  bf16_t* ao = xb;               // alias: xb dead once proj5 completes
  bf16_t* wb = ws + 6 * NELEM;   // 6 bf16 weights [wq1,wk1,wq2,wk2,wv,wo]

  // one-time: allow 128 KiB dynamic LDS for the 8-phase GEMM
  static bool attr_set = false;
  if (!attr_set) {
    (void)hipFuncSetAttribute(reinterpret_cast<const void*>(proj5_kernel),
                              hipFuncAttributeMaxDynamicSharedMemorySize, 131072);
    attr_set = true;
  }

  cvt7_kernel<<<dim3(4096, 7), dim3(256), 0, stream>>>(
      x, wq1, wk1, wq2, wk2, wv, wo, xb, wb);
  proj5_kernel<<<dim3(128, 5), dim3(512), 131072, stream>>>(
      xb, wb, q1, k1, q2, k2, vt);
  diff_attn_kernel<<<dim3(BATCH * NHEADS * (SEQ / 64)), dim3(256), 0, stream>>>(
      q1, k1, q2, k2, vt, lam, ao);
  gemm_out_kernel<<<dim3(NTOK / 128, D_MODEL / 128), dim3(256), 16384, stream>>>(
      ao, wb + 5 * D2, (float*)d_out);
}

// Round 7
// 509.357 us; speedup vs baseline: 2.4908x; 1.7542x over previous
//
#include <hip/hip_runtime.h>
#include <hip/hip_bf16.h>
#include <stdint.h>

typedef __bf16 bf16_t;
typedef __bf16 bf16x8 __attribute__((ext_vector_type(8)));
typedef float f32x4 __attribute__((ext_vector_type(4)));

#define D_MODEL 2048
#define SEQ     2048
#define NHEADS  16
#define HDIM    128
#define BATCH   2
#define NTOK    (BATCH * SEQ)                       // 4096
#define NELEM   ((size_t)BATCH * SEQ * D_MODEL)     // 8388608
#define D2      ((size_t)D_MODEL * D_MODEL)         // 4194304

// ---------------------------------------------------------------------------
// fp32 -> bf16 convert pass: x + 6 weights, 8 elems/thread, float4 loads.
// ---------------------------------------------------------------------------
__global__ void __launch_bounds__(256)
cvt7_kernel(const float* __restrict__ x,
            const float* __restrict__ w0, const float* __restrict__ w1,
            const float* __restrict__ w2, const float* __restrict__ w3,
            const float* __restrict__ w4, const float* __restrict__ w5,
            bf16_t* __restrict__ xb, bf16_t* __restrict__ wb) {
  const int y = blockIdx.y;
  const float* srcs[7] = {x, w0, w1, w2, w3, w4, w5};
  const float* src = srcs[y];
  bf16_t* dst = (y == 0) ? xb : wb + (size_t)(y - 1) * D2;
  const size_t n = (y == 0) ? NELEM : D2;
  const size_t base = ((size_t)blockIdx.x * 256 + threadIdx.x) * 8;
  if (base >= n) return;
  f32x4 lo = *(const f32x4*)(src + base);
  f32x4 hi = *(const f32x4*)(src + base + 4);
  union { bf16x8 v; bf16_t h[8]; } u;
#pragma unroll
  for (int j = 0; j < 4; j++) {
    u.h[j]     = (bf16_t)lo[j];
    u.h[j + 4] = (bf16_t)hi[j];
  }
  *(bf16x8*)(dst + base) = u.v;
}

// ---------------------------------------------------------------------------
// async global->LDS 16B helper (global_load_lds_dwordx4).
// ---------------------------------------------------------------------------
__device__ __forceinline__ void async_load16(const void* g, void* l) {
  __builtin_amdgcn_global_load_lds(
      (const __attribute__((address_space(1))) void*)g,
      (__attribute__((address_space(3))) void*)l, 16, 0, 0);
}

// ---------------------------------------------------------------------------
// Legacy 128x128 tile body (m97 structure) — kept for gemm_out (512 wgs of
// 128^2 tile = exactly 2 full occupancy rounds).
// ---------------------------------------------------------------------------
template <int TRANS, typename TC>
__device__ __forceinline__ void gemm_tile_body(const bf16_t* __restrict__ A,
                                               const bf16_t* __restrict__ W,
                                               TC* __restrict__ C) {
  extern __shared__ char smem[];
  bf16_t* As = (bf16_t*)smem;
  bf16_t* Bs = (bf16_t*)smem + 128 * 32;
  const int K = D_MODEL, N = D_MODEL;
  const int tid  = threadIdx.x;
  const int wave = tid >> 6, lane = tid & 63;
  const int quad = lane >> 4, l16 = lane & 15;
  const int tm = blockIdx.x * 128, tn = blockIdx.y * 128;
  const int wm = (wave & 1) * 64, wn = (wave >> 1) * 64;

  f32x4 acc[4][4];
#pragma unroll
  for (int i = 0; i < 4; i++)
#pragma unroll
    for (int j = 0; j < 4; j++) acc[i][j] = (f32x4){0.f, 0.f, 0.f, 0.f};

  const int srow = lane >> 2;
  const int scol = (lane & 3) * 8;

  for (int k0 = 0; k0 < K; k0 += 32) {
    __syncthreads();
#pragma unroll
    for (int i = 0; i < 2; i++) {
      const int rbase = (i * 4 + wave) * 16;
      async_load16(A + (size_t)(tm + rbase + srow) * K + k0 + scol, As + rbase * 32);
      async_load16(W + (size_t)(tn + rbase + srow) * K + k0 + scol, Bs + rbase * 32);
    }
    __syncthreads();

    bf16x8 af[4], bfr[4];
#pragma unroll
    for (int i = 0; i < 4; i++)
      af[i] = *(const bf16x8*)(As + (wm + i * 16 + l16) * 32 + quad * 8);
#pragma unroll
    for (int j = 0; j < 4; j++)
      bfr[j] = *(const bf16x8*)(Bs + (wn + j * 16 + l16) * 32 + quad * 8);
#pragma unroll
    for (int i = 0; i < 4; i++)
#pragma unroll
      for (int j = 0; j < 4; j++)
        acc[i][j] = __builtin_amdgcn_mfma_f32_16x16x32_bf16(af[i], bfr[j], acc[i][j], 0, 0, 0);
  }

#pragma unroll
  for (int i = 0; i < 4; i++) {
    const int r0 = wm + i * 16 + quad * 4;
#pragma unroll
    for (int j = 0; j < 4; j++) {
      const int c = tn + wn + j * 16 + l16;
      if constexpr (TRANS) {
        const int m = tm + r0;
        const int b = m >> 11;
        const int s = m & (SEQ - 1);
        union { bf16_t h[4]; uint2 u2; } p;
#pragma unroll
        for (int r = 0; r < 4; r++) p.h[r] = (bf16_t)acc[i][j][r];
        *(uint2*)((bf16_t*)C + (size_t)(b * D_MODEL + c) * SEQ + s) = p.u2;
      } else {
#pragma unroll
        for (int r = 0; r < 4; r++)
          C[(size_t)(tm + r0 + r) * N + c] = (TC)acc[i][j][r];
      }
    }
  }
}

__global__ void __launch_bounds__(256)
gemm_out_kernel(const bf16_t* __restrict__ A, const bf16_t* __restrict__ W,
                float* __restrict__ C) {
  gemm_tile_body<0, float>(A, W, C);
}

// ---------------------------------------------------------------------------
// 256x256 8-phase GEMM body (m201 template, plain HIP). Unchanged.
// ---------------------------------------------------------------------------
template <int TRANS, typename TC>
__device__ __forceinline__ void gemm256_body(const bf16_t* __restrict__ A,
                                             const bf16_t* __restrict__ W,
                                             TC* __restrict__ C,
                                             const int tm, const int tn) {
  extern __shared__ char smem[];
  constexpr int K = D_MODEL;
  constexpr int NT = K / 64;   // 32 K-tiles
  const int tid = threadIdx.x;
  const int wid = tid >> 6, lane = tid & 63;
  const int quad = lane >> 4, l16 = lane & 15;
  const int wm = wid >> 2, wn = wid & 3;

  const int sr = lane >> 2;
  const int sc = (lane & 3) ^ ((lane >> 4) & 2);
  const int rdoff = (l16 * 64 + quad * 16) ^ ((l16 & 8) << 2);

  f32x4 acc[8][4];
#pragma unroll
  for (int i = 0; i < 8; i++)
#pragma unroll
    for (int j = 0; j < 4; j++) acc[i][j] = (f32x4){0.f, 0.f, 0.f, 0.f};

  bf16x8 af[2][4], bfA[2][2], bfB[2][2];

#define STAGE256(P, rowbase, ldsbase, h, t)                                      \
  {                                                                              \
    const bf16_t* _s = (P) + (size_t)((rowbase) + (h) * 128 + wid * 16 + sr) * K \
                           + ((t) * 64 + sc * 8);                                \
    char* _d = smem + (ldsbase) + (h) * 16384 + wid * 2048;                      \
    async_load16(_s, _d);                                                        \
    async_load16(_s + 32, _d + 1024);                                            \
  }

#define LDA256(c, rh)                                                            \
  _Pragma("unroll") for (int ks = 0; ks < 2; ks++)                               \
  _Pragma("unroll") for (int j = 0; j < 4; j++)                                  \
      af[ks][j] = *(const bf16x8*)(smem + (c) * 65536 +                          \
                  ((wm * 8 + (rh) * 4 + j) * 2 + ks) * 1024 + rdoff);

#define LDB256(c, dst, cf0)                                                      \
  _Pragma("unroll") for (int ks = 0; ks < 2; ks++)                               \
  _Pragma("unroll") for (int j = 0; j < 2; j++)                                  \
      dst[ks][j] = *(const bf16x8*)(smem + (c) * 65536 + 32768 +                 \
                   ((wn * 4 + (cf0) + j) * 2 + ks) * 1024 + rdoff);

#define MFMA16(rh, bfr, cb)                                                      \
  _Pragma("unroll") for (int j = 0; j < 4; j++)                                  \
  _Pragma("unroll") for (int cf = 0; cf < 2; cf++)                               \
  _Pragma("unroll") for (int ks = 0; ks < 2; ks++)                               \
      acc[(rh) * 4 + j][(cb) + cf] = __builtin_amdgcn_mfma_f32_16x16x32_bf16(    \
          af[ks][j], bfr[ks][cf], acc[(rh) * 4 + j][(cb) + cf], 0, 0, 0);

#define BAR256() __builtin_amdgcn_s_barrier()
#define LGKM0()                                                                  \
  { asm volatile("s_waitcnt lgkmcnt(0)" ::: "memory");                           \
    __builtin_amdgcn_sched_barrier(0); }
#define VMW4()                                                                   \
  { asm volatile("s_waitcnt vmcnt(4)" ::: "memory");                             \
    __builtin_amdgcn_sched_barrier(0); }
#define VMW0()                                                                   \
  { asm volatile("s_waitcnt vmcnt(0)" ::: "memory");                             \
    __builtin_amdgcn_sched_barrier(0); }

  STAGE256(A, tm, 0,     0, 0); STAGE256(A, tm, 0,     1, 0);
  STAGE256(W, tn, 32768, 0, 0); STAGE256(W, tn, 32768, 1, 0);
  STAGE256(W, tn, 98304, 0, 1); STAGE256(W, tn, 98304, 1, 1);
  VMW4();
  BAR256();

  for (int it = 0; it < NT / 2; ++it) {
    const int kt = 2 * it;
    const int t2 = (kt + 2 < NT) ? kt + 2 : 0;
    const int t3 = (kt + 3 < NT) ? kt + 3 : 0;

    // P1
    LDA256(0, 0); LDB256(0, bfA, 0);
    STAGE256(A, tm, 65536, 0, kt + 1);
    BAR256(); LGKM0();
    __builtin_amdgcn_s_setprio(1); MFMA16(0, bfA, 0); __builtin_amdgcn_s_setprio(0);
    BAR256();
    // P2
    LDB256(0, bfB, 2);
    STAGE256(A, tm, 65536, 1, kt + 1);
    BAR256(); LGKM0();
    __builtin_amdgcn_s_setprio(1); MFMA16(0, bfB, 2); __builtin_amdgcn_s_setprio(0);
    BAR256();
    // P3
    LDA256(0, 1);
    STAGE256(W, tn, 32768, 0, t2);
    BAR256(); LGKM0();
    __builtin_amdgcn_s_setprio(1); MFMA16(1, bfA, 0); __builtin_amdgcn_s_setprio(0);
    BAR256();
    // P4
    STAGE256(W, tn, 32768, 1, t2);
    BAR256();
    __builtin_amdgcn_s_setprio(1); MFMA16(1, bfB, 2); __builtin_amdgcn_s_setprio(0);
    VMW4();
    BAR256();
    // P5
    LDA256(1, 0); LDB256(1, bfA, 0);
    STAGE256(A, tm, 0, 0, t2);
    BAR256(); LGKM0();
    __builtin_amdgcn_s_setprio(1); MFMA16(0, bfA, 0); __builtin_amdgcn_s_setprio(0);
    BAR256();
    // P6
    LDB256(1, bfB, 2);
    STAGE256(A, tm, 0, 1, t2);
    BAR256(); LGKM0();
    __builtin_amdgcn_s_setprio(1); MFMA16(0, bfB, 2); __builtin_amdgcn_s_setprio(0);
    BAR256();
    // P7
    LDA256(1, 1);
    STAGE256(W, tn, 98304, 0, t3);
    BAR256(); LGKM0();
    __builtin_amdgcn_s_setprio(1); MFMA16(1, bfA, 0); __builtin_amdgcn_s_setprio(0);
    BAR256();
    // P8
    STAGE256(W, tn, 98304, 1, t3);
    BAR256();
    __builtin_amdgcn_s_setprio(1); MFMA16(1, bfB, 2); __builtin_amdgcn_s_setprio(0);
    VMW4();
    BAR256();
  }
  VMW0();

#pragma unroll
  for (int rf = 0; rf < 8; rf++) {
    const int r0 = wm * 128 + rf * 16 + quad * 4;
#pragma unroll
    for (int cf = 0; cf < 4; cf++) {
      const int c = tn + wn * 64 + cf * 16 + l16;
      if constexpr (TRANS) {
        const int m = tm + r0;
        const int b = m >> 11;
        const int s = m & (SEQ - 1);
        union { bf16_t h[4]; uint2 u2; } p;
#pragma unroll
        for (int r = 0; r < 4; r++) p.h[r] = (bf16_t)acc[rf][cf][r];
        *(uint2*)((bf16_t*)C + (size_t)(b * D_MODEL + c) * SEQ + s) = p.u2;
      } else {
#pragma unroll
        for (int r = 0; r < 4; r++)
          C[(size_t)(tm + r0 + r) * D_MODEL + c] = (TC)acc[rf][cf][r];
      }
    }
  }
#undef STAGE256
#undef LDA256
#undef LDB256
#undef MFMA16
#undef BAR256
#undef LGKM0
#undef VMW4
#undef VMW0
}

__global__ void __launch_bounds__(512, 2)
proj5_kernel(const bf16_t* __restrict__ xb, const bf16_t* __restrict__ wb,
             bf16_t* __restrict__ q1, bf16_t* __restrict__ k1,
             bf16_t* __restrict__ q2, bf16_t* __restrict__ k2,
             bf16_t* __restrict__ vt) {
  const int g = blockIdx.y;
  const int orig = blockIdx.x;
  const int wg = (orig & 7) * 16 + (orig >> 3);
  const int tm = (wg & 15) * 256;
  const int tn = (wg >> 4) * 256;
  const bf16_t* w = wb + (size_t)g * D2;
  if (g == 4) {
    gemm256_body<1, bf16_t>(xb, w, vt, tm, tn);
  } else {
    bf16_t* o = (g == 0) ? q1 : (g == 1) ? k1 : (g == 2) ? q2 : k2;
    gemm256_body<0, bf16_t>(xb, w, o, tm, tn);
  }
}

// ---------------------------------------------------------------------------
// Differential flash attention, v10: v7 compute + T3/T4 double-buffered
//  global_load_lds pipeline (zero staged VGPR state — v8/v9 reg-staging
//  spilled regardless of launch_bounds: allocator demotes live-across-
//  barrier arrays; WRITE_SIZE 1.5-2GB signature twice).
//  LDS 80 KB = K1[2x16K] + K2[2x16K] + V[16K] -> exactly 2 blocks/CU
//  (= v7's measured occupancy; no loss). Per tile, per wave:
//   top:   STAGE_K(t+1 -> alt buf)            (8 DMA)
//          vmcnt(12) [K(t) landed; V(t)+K(t+1) fly] + s_barrier
//          QK from Kbuf[t&1], softmax
//          vmcnt(8)  [V(t) landed; K(t+1) flies]    + s_barrier
//          PV from Vs
//          s_barrier; STAGE_V(t+1)            (4 DMA)
//  K hides under a full tile; V under QK+softmax; no vmcnt(0) in loop.
//  Tail via clamped dummy stages (uniform counts); epilogue __syncthreads
//  drains them. sched_barrier(0) after every wait/barrier (rule 18).
// ---------------------------------------------------------------------------
__global__ void __launch_bounds__(256, 2)
diff_attn_kernel(const bf16_t* __restrict__ q1g, const bf16_t* __restrict__ k1g,
                 const bf16_t* __restrict__ q2g, const bf16_t* __restrict__ k2g,
                 const bf16_t* __restrict__ vtg, const float* __restrict__ lamg,
                 bf16_t* __restrict__ outg) {
  const int blk = blockIdx.x;            // 1024 blocks
  const int xcd = blk & 7;
  const int idx = blk >> 3;
  const int bh  = xcd * 4 + (idx >> 5);
  const int qt  = idx & 31;              // 32 q-tiles of 64
  const int b = bh >> 4, h = bh & 15;
  const int tid = threadIdx.x, wave = tid >> 6, lane = tid & 63;
  const int quad = lane >> 4, l16 = lane & 15;
  const int stream = wave >> 1;          // 0: (q1,k1)   1: (q2,k2)
  const int wq     = wave & 1;           // query half of the 64-row tile
  const int q0 = qt * 64 + wq * 32;      // this wave's 32 queries

  __shared__ char smem_all[81920];
  bf16_t* K1b = (bf16_t*)smem_all;               // 2 x 16 KB (buf*8192 elems)
  bf16_t* K2b = (bf16_t*)(smem_all + 32768);     // 2 x 16 KB
  bf16_t* Vs  = (bf16_t*)(smem_all + 65536);     // 16 KB single buffer

  const bf16_t* k1p = k1g + (size_t)b * SEQ * D_MODEL + h * HDIM;
  const bf16_t* k2p = k2g + (size_t)b * SEQ * D_MODEL + h * HDIM;
  const bf16_t* vtp = vtg + ((size_t)b * D_MODEL + h * HDIM) * SEQ;
  const bf16_t* qp  = (stream ? q2g : q1g) +
                      ((size_t)b * SEQ + q0) * D_MODEL + h * HDIM;
  const bf16_t* Ksb = stream ? K2b : K1b;        // this stream's buffer pair

  // Q fragments for this wave's stream: set a = q0..q0+15, set b = +16..31.
  bf16x8 aqa[4], aqb[4];
#pragma unroll
  for (int c = 0; c < 4; c++) {
    aqa[c] = *(const bf16x8*)(qp + (size_t)l16 * D_MODEL + c * 32 + quad * 8);
    aqb[c] = *(const bf16x8*)(qp + (size_t)(16 + l16) * D_MODEL + c * 32 + quad * 8);
  }

  f32x4 Oa[8], Ob[8];
#pragma unroll
  for (int n = 0; n < 8; n++) {
    Oa[n] = (f32x4){0.f, 0.f, 0.f, 0.f};
    Ob[n] = (f32x4){0.f, 0.f, 0.f, 0.f};
  }
  float la = 0.f, lb = 0.f;

  const float c2 = 0.0883883476483184f * 1.4426950408889634f;  // log2(e)/sqrt(128)

  // staging lane decompositions (identical to v4-v7)
  const int k_r  = lane >> 4;
  const int k_p  = lane & 15;
  const int v_r  = lane >> 3;
  const int v_p  = lane & 7;

#define STAGE_K(KT, BUF)                                                         \
  { _Pragma("unroll") for (int i = 0; i < 4; i++) {                              \
      const int krb = wave * 16 + i * 4;                                         \
      const int kr  = krb + k_r;                                                 \
      const int kkey = (((kr >> 2) & 3) << 3) | (((kr >> 4) & 1) << 2) |         \
                       (kr & 3) | (kr & 32);                                     \
      const int kg = k_p ^ (kr & 7);                                             \
      async_load16(k1p + (size_t)((KT) + kkey) * D_MODEL + kg * 8,               \
                   K1b + (BUF) * 8192 + krb * 128);                              \
      async_load16(k2p + (size_t)((KT) + kkey) * D_MODEL + kg * 8,               \
                   K2b + (BUF) * 8192 + krb * 128);                              \
  } }

#define STAGE_V(KT)                                                              \
  { _Pragma("unroll") for (int i = 0; i < 4; i++) {                              \
      const int vrb = wave * 32 + i * 8;                                         \
      const int vr  = vrb + v_r;                                                 \
      const int vg  = v_p ^ (vr & 7);                                            \
      async_load16(vtp + (size_t)vr * SEQ + (KT) + vg * 8, Vs + vrb * 64);       \
  } }

#define VMW(N)                                                                   \
  { asm volatile("s_waitcnt vmcnt(" #N ")" ::: "memory");                        \
    __builtin_amdgcn_sched_barrier(0); }
#define BARR()                                                                   \
  { __builtin_amdgcn_s_barrier();                                                \
    __builtin_amdgcn_sched_barrier(0); }

  // ---- prologue: stage tile 0 fully, drain, sync ----
  STAGE_K(0, 0);
  STAGE_V(0);
  VMW(0); BARR();

  for (int t = 0; t < SEQ / 64; ++t) {
    const int ktn = (t < SEQ / 64 - 1) ? (t + 1) * 64 : 0;  // clamped dummy ok
    STAGE_K(ktn, (t + 1) & 1);
    VMW(12);          // K(t) landed (V(t)=4 + K(t+1)=8 may fly)
    BARR();           // all waves' K(t) visible

    const bf16_t* Kc = Ksb + (t & 1) * 8192;
    const int xsw = l16 & 7;

    // ---- S^T: all 4 subtiles live, c-outer -> 8 indep MFMA chains ----
    f32x4 sa[4], sb[4];
#pragma unroll
    for (int s = 0; s < 4; s++) {
      sa[s] = (f32x4){0.f, 0.f, 0.f, 0.f};
      sb[s] = (f32x4){0.f, 0.f, 0.f, 0.f};
    }
    __builtin_amdgcn_s_setprio(1);
#pragma unroll
    for (int c = 0; c < 4; c++) {
      const int pos = ((c * 4 + quad) ^ xsw) * 8;
#pragma unroll
      for (int s = 0; s < 4; s++) {
        bf16x8 f = *(const bf16x8*)(Kc + (s * 16 + l16) * 128 + pos);
        sa[s] = __builtin_amdgcn_mfma_f32_16x16x32_bf16(f, aqa[c], sa[s], 0, 0, 0);
        sb[s] = __builtin_amdgcn_mfma_f32_16x16x32_bf16(f, aqb[c], sb[s], 0, 0, 0);
      }
    }
    __builtin_amdgcn_s_setprio(0);

    // ---- softmax pack, both halves (releases sa/sb before PV) ----
    union { bf16x8 v; bf16_t h[8]; } pa[2], pb[2];
#pragma unroll
    for (int s = 0; s < 4; s++) {
#pragma unroll
      for (int r = 0; r < 4; r++) {
        const float ea = __builtin_amdgcn_exp2f(sa[s][r] * c2);
        const float eb = __builtin_amdgcn_exp2f(sb[s][r] * c2);
        pa[s >> 1].h[(s & 1) * 4 + r] = (bf16_t)ea; la += ea;
        pb[s >> 1].h[(s & 1) * 4 + r] = (bf16_t)eb; lb += eb;
      }
    }

    VMW(8);           // V(t) landed (K(t+1)=8 may fly)
    BARR();           // all waves' V(t) visible

    // ---- PV: one V-frag read feeds 2 MFMAs; 16 indep chains ----
    __builtin_amdgcn_s_setprio(1);
#pragma unroll
    for (int half = 0; half < 2; half++) {
      const int vpos = ((half * 4 + quad) ^ xsw) * 8;
#pragma unroll
      for (int n = 0; n < 8; n++) {
        bf16x8 vf = *(const bf16x8*)(Vs + (n * 16 + l16) * 64 + vpos);
        Oa[n] = __builtin_amdgcn_mfma_f32_16x16x32_bf16(pa[half].v, vf, Oa[n], 0, 0, 0);
        Ob[n] = __builtin_amdgcn_mfma_f32_16x16x32_bf16(pb[half].v, vf, Ob[n], 0, 0, 0);
      }
    }
    __builtin_amdgcn_s_setprio(0);

    BARR();           // all waves done reading Vs (and K(t) buf long done)
    STAGE_V(ktn);     // V(t+1) flies under next QK+softmax
  }
#undef STAGE_K
#undef STAGE_V
#undef VMW
#undef BARR

  // ---- denominators (per set, within wave) ----
  la += __shfl_xor(la, 16); la += __shfl_xor(la, 32);
  lb += __shfl_xor(lb, 16); lb += __shfl_xor(lb, 32);

  // ---- cross-stream combine through LDS (reuse retired K buffers) ----
  __syncthreads();                       // drains dummy DMAs (vmcnt 0) + sync
  float* xfer = (float*)smem_all;        // 64 rows x 128 f32 = 32 KB

  if (stream == 1) {
    const float lam = lamg[h];
    const float ia = lam / la, ib = lam / lb;
    float iao[4], ibo[4];
#pragma unroll
    for (int r = 0; r < 4; r++) {
      iao[r] = __shfl(ia, quad * 4 + r, 16);
      ibo[r] = __shfl(ib, quad * 4 + r, 16);
    }
#pragma unroll
    for (int r = 0; r < 4; r++)
#pragma unroll
      for (int n = 0; n < 8; n++) {
        xfer[(wq * 32 + quad * 4 + r) * 128 + n * 16 + l16] = Oa[n][r] * iao[r];
        xfer[(wq * 32 + 16 + quad * 4 + r) * 128 + n * 16 + l16] = Ob[n][r] * ibo[r];
      }
  }
  __syncthreads();
  if (stream == 0) {
    const float ia = 1.f / la, ib = 1.f / lb;
    float iao[4], ibo[4];
#pragma unroll
    for (int r = 0; r < 4; r++) {
      iao[r] = __shfl(ia, quad * 4 + r, 16);
      ibo[r] = __shfl(ib, quad * 4 + r, 16);
    }
    bf16_t* op = outg + ((size_t)b * SEQ + q0) * D_MODEL + h * HDIM;
#pragma unroll
    for (int r = 0; r < 4; r++)
#pragma unroll
      for (int n = 0; n < 8; n++) {
        const float va = Oa[n][r] * iao[r] -
                         xfer[(wq * 32 + quad * 4 + r) * 128 + n * 16 + l16];
        const float vb = Ob[n][r] * ibo[r] -
                         xfer[(wq * 32 + 16 + quad * 4 + r) * 128 + n * 16 + l16];
        op[(size_t)(quad * 4 + r) * D_MODEL + n * 16 + l16] = (bf16_t)va;
        op[(size_t)(16 + quad * 4 + r) * D_MODEL + n * 16 + l16] = (bf16_t)vb;
      }
  }
}

// ---------------------------------------------------------------------------
extern "C" void kernel_launch(void* const* d_in, const int* in_sizes, int n_in,
                              void* d_out, int out_size, void* d_ws, size_t ws_size,
                              hipStream_t stream) {
  const float* x   = (const float*)d_in[0];
  const float* wq1 = (const float*)d_in[1];
  const float* wk1 = (const float*)d_in[2];
  const float* wq2 = (const float*)d_in[3];
  const float* wk2 = (const float*)d_in[4];
  const float* wv  = (const float*)d_in[5];
  const float* wo  = (const float*)d_in[6];
  const float* lam = (const float*)d_in[7];

  bf16_t* ws = (bf16_t*)d_ws;
  bf16_t* q1 = ws + 0 * NELEM;
  bf16_t* k1 = ws + 1 * NELEM;
  bf16_t* q2 = ws + 2 * NELEM;
  bf16_t* k2 = ws + 3 * NELEM;
  bf16_t* vt = ws + 4 * NELEM;   // [B, D, S] channel-major (V transposed)
  bf16_t* xb = ws + 5 * NELEM;   // bf16 copy of x; later reused as `ao`
  bf16_t* ao = xb;               // alias: xb dead once proj5 completes
  bf16_t* wb = ws + 6 * NELEM;   // 6 bf16 weights [wq1,wk1,wq2,wk2,wv,wo]

  // one-time: allow 128 KiB dynamic LDS for the 8-phase GEMM
  static bool attr_set = false;
  if (!attr_set) {
    (void)hipFuncSetAttribute(reinterpret_cast<const void*>(proj5_kernel),
                              hipFuncAttributeMaxDynamicSharedMemorySize, 131072);
    attr_set = true;
  }

  cvt7_kernel<<<dim3(4096, 7), dim3(256), 0, stream>>>(
      x, wq1, wk1, wq2, wk2, wv, wo, xb, wb);
  proj5_kernel<<<dim3(128, 5), dim3(512), 131072, stream>>>(
      xb, wb, q1, k1, q2, k2, vt);
  diff_attn_kernel<<<dim3(BATCH * NHEADS * (SEQ / 64)), dim3(256), 0, stream>>>(
      q1, k1, q2, k2, vt, lam, ao);
  gemm_out_kernel<<<dim3(NTOK / 128, D_MODEL / 128), dim3(256), 16384, stream>>>(
      ao, wb + 5 * D2, (float*)d_out);
}